// Round 7
// baseline (55.831 us; speedup 1.0000x reference)
//
#include <hip/hip_runtime.h>

#define D_SAMPLE 256
#define KCLIENTS 64
#define NH 128     // hidden dim
#define PF 8       // fuse: rows prefetched to registers before softmax
#define BLOCK 256

typedef float vfloat4 __attribute__((ext_vector_type(4)));

// ---------------- Kernel 1: per-client attention scores ----------------
// grid = 64 blocks (one per client k), block = 1024 threads:
// t -> (q = t>>7: one of 8 i-slices of the 512 inputs, j = t&127: hidden unit).
__global__ __launch_bounds__(1024)
void lf_scores_kernel(const float* __restrict__ client,
                      const float* __restrict__ globalt,
                      const float* __restrict__ W1,
                      const float* __restrict__ b1,
                      const float* __restrict__ W2,
                      const float* __restrict__ b2,
                      float* __restrict__ scores,
                      int D) {
    const int k = blockIdx.x;
    const int t = threadIdx.x;   // 0..1023

    __shared__ float attn[2 * D_SAMPLE];
    __shared__ float ph[8][NH];
    __shared__ float red[2];

    if (t < D_SAMPLE)            attn[t] = client[(size_t)k * D + t];
    else if (t < 2 * D_SAMPLE)   attn[t] = globalt[t - D_SAMPLE];
    __syncthreads();

    const int q = t >> 7;        // i-slice 0..7 (64 inputs each)
    const int j = t & (NH - 1);  // hidden unit
    const float* __restrict__ w1p = W1 + (size_t)(q * 64) * NH + j;
    const float* __restrict__ xp  = attn + q * 64;

    float a0 = 0.f, a1 = 0.f;
#pragma unroll 8
    for (int i = 0; i < 64; i += 2) {
        a0 = fmaf(xp[i],     w1p[(size_t)i * NH],       a0);
        a1 = fmaf(xp[i + 1], w1p[(size_t)(i + 1) * NH], a1);
    }
    ph[q][j] = a0 + a1;
    __syncthreads();

    if (t < NH) {
        float h = b1[j];
#pragma unroll
        for (int r = 0; r < 8; ++r) h += ph[r][j];
        h = fmaxf(h, 0.0f);
        float v = h * W2[j];
#pragma unroll
        for (int off = 32; off > 0; off >>= 1)
            v += __shfl_down(v, off, 64);
        if ((t & 63) == 0) red[t >> 6] = v;
    }
    __syncthreads();
    if (t == 0) scores[k] = red[0] + red[1] + b2[0];
}

// ---------------- Kernel 2: softmax (in-block) + weighted fuse ----------------
// Each thread handles TWO float4 elements (d0, d0+BLOCK) for 2x memory ILP.
// First PF row-loads (both halves) + global_token issued into registers
// BEFORE the softmax; out stored nontemporally.
__global__ __launch_bounds__(BLOCK)
void lf_fuse_kernel(const float* __restrict__ client,
                    const float* __restrict__ globalt,
                    const float* __restrict__ scores,
                    float* __restrict__ out,
                    int D4) {
    __shared__ float w[KCLIENTS];
    const int t = threadIdx.x;
    const int d0 = blockIdx.x * (2 * BLOCK) + t;
    const int d1 = d0 + BLOCK;
    const bool a0v = (d0 < D4);
    const bool a1v = (d1 < D4);

    const float4* __restrict__ c4 = (const float4*)client;
    const float4* __restrict__ g4 = (const float4*)globalt;
    vfloat4* __restrict__ o4 = (vfloat4*)out;

    // issue first PF row loads + global token (independent of weights)
    float4 pre0[PF], pre1[PF], g0, g1;
    if (a0v) {
#pragma unroll
        for (int k = 0; k < PF; ++k) pre0[k] = c4[(size_t)k * D4 + d0];
        g0 = g4[d0];
    }
    if (a1v) {
#pragma unroll
        for (int k = 0; k < PF; ++k) pre1[k] = c4[(size_t)k * D4 + d1];
        g1 = g4[d1];
    }

    // wave 0: softmax over the 64 scores (L2-hot) while loads are in flight
    if (t < KCLIENTS) {
        float s = scores[t];
        float m = s;
#pragma unroll
        for (int off = 32; off > 0; off >>= 1)
            m = fmaxf(m, __shfl_xor(m, off, 64));
        float e = __expf(s - m);
        float sum = e;
#pragma unroll
        for (int off = 32; off > 0; off >>= 1)
            sum += __shfl_xor(sum, off, 64);
        w[t] = e / sum;
    }
    __syncthreads();

    float4 acc0 = make_float4(0.f, 0.f, 0.f, 0.f);
    float4 acc1 = make_float4(0.f, 0.f, 0.f, 0.f);
#pragma unroll
    for (int k = 0; k < PF; ++k) {
        const float wk = w[k];
        if (a0v) {
            acc0.x = fmaf(wk, pre0[k].x, acc0.x);
            acc0.y = fmaf(wk, pre0[k].y, acc0.y);
            acc0.z = fmaf(wk, pre0[k].z, acc0.z);
            acc0.w = fmaf(wk, pre0[k].w, acc0.w);
        }
        if (a1v) {
            acc1.x = fmaf(wk, pre1[k].x, acc1.x);
            acc1.y = fmaf(wk, pre1[k].y, acc1.y);
            acc1.z = fmaf(wk, pre1[k].z, acc1.z);
            acc1.w = fmaf(wk, pre1[k].w, acc1.w);
        }
    }
#pragma unroll 4
    for (int k = PF; k < KCLIENTS; ++k) {
        const float wk = w[k];
        if (a0v) {
            const float4 c = c4[(size_t)k * D4 + d0];
            acc0.x = fmaf(wk, c.x, acc0.x);
            acc0.y = fmaf(wk, c.y, acc0.y);
            acc0.z = fmaf(wk, c.z, acc0.z);
            acc0.w = fmaf(wk, c.w, acc0.w);
        }
        if (a1v) {
            const float4 c = c4[(size_t)k * D4 + d1];
            acc1.x = fmaf(wk, c.x, acc1.x);
            acc1.y = fmaf(wk, c.y, acc1.y);
            acc1.z = fmaf(wk, c.z, acc1.z);
            acc1.w = fmaf(wk, c.w, acc1.w);
        }
    }
    if (a0v) {
        vfloat4 r;
        r.x = 0.5f * g0.x + 0.5f * acc0.x;
        r.y = 0.5f * g0.y + 0.5f * acc0.y;
        r.z = 0.5f * g0.z + 0.5f * acc0.z;
        r.w = 0.5f * g0.w + 0.5f * acc0.w;
        __builtin_nontemporal_store(r, &o4[d0]);
    }
    if (a1v) {
        vfloat4 r;
        r.x = 0.5f * g1.x + 0.5f * acc1.x;
        r.y = 0.5f * g1.y + 0.5f * acc1.y;
        r.z = 0.5f * g1.z + 0.5f * acc1.z;
        r.w = 0.5f * g1.w + 0.5f * acc1.w;
        __builtin_nontemporal_store(r, &o4[d1]);
    }
}

extern "C" void kernel_launch(void* const* d_in, const int* in_sizes, int n_in,
                              void* d_out, int out_size, void* d_ws, size_t ws_size,
                              hipStream_t stream) {
    const float* client  = (const float*)d_in[0];  // [64, D]
    const float* globalt = (const float*)d_in[1];  // [1, D]
    const float* W1      = (const float*)d_in[2];  // [512, 128]
    const float* b1      = (const float*)d_in[3];  // [128]
    const float* W2      = (const float*)d_in[4];  // [128, 1]
    const float* b2      = (const float*)d_in[5];  // [1]
    float* out = (float*)d_out;                    // [1, D]

    const int D  = in_sizes[0] / KCLIENTS;         // 1,000,000
    const int D4 = D / 4;                          // 250,000

    float* scores = (float*)d_ws;                  // 64 floats

    lf_scores_kernel<<<KCLIENTS, 1024, 0, stream>>>(client, globalt, W1, b1, W2, b2,
                                                    scores, D);

    const int grid = (D4 + 2 * BLOCK - 1) / (2 * BLOCK);   // 489
    lf_fuse_kernel<<<grid, BLOCK, 0, stream>>>(client, globalt, scores, out, D4);
}

// Round 9
// 48.672 us; speedup vs baseline: 1.1471x; 1.1471x over previous
//
#include <hip/hip_runtime.h>

#define D_SAMPLE 256
#define KCLIENTS 64
#define NH 128     // hidden dim
#define PF 8       // fuse: rows prefetched to registers before softmax
#define BLOCK 256

typedef float vfloat4 __attribute__((ext_vector_type(4)));

// ---------------- Kernel 1: per-client attention scores ----------------
// grid = 64 blocks (one per client k), block = 1024 threads:
// t -> (q = t>>7: one of 8 i-slices of the 512 inputs, j = t&127: hidden unit).
__global__ __launch_bounds__(1024)
void lf_scores_kernel(const float* __restrict__ client,
                      const float* __restrict__ globalt,
                      const float* __restrict__ W1,
                      const float* __restrict__ b1,
                      const float* __restrict__ W2,
                      const float* __restrict__ b2,
                      float* __restrict__ scores,
                      int D) {
    const int k = blockIdx.x;
    const int t = threadIdx.x;   // 0..1023

    __shared__ float attn[2 * D_SAMPLE];
    __shared__ float ph[8][NH];
    __shared__ float red[2];

    if (t < D_SAMPLE)            attn[t] = client[(size_t)k * D + t];
    else if (t < 2 * D_SAMPLE)   attn[t] = globalt[t - D_SAMPLE];
    __syncthreads();

    const int q = t >> 7;        // i-slice 0..7 (64 inputs each)
    const int j = t & (NH - 1);  // hidden unit
    const float* __restrict__ w1p = W1 + (size_t)(q * 64) * NH + j;
    const float* __restrict__ xp  = attn + q * 64;

    float a0 = 0.f, a1 = 0.f;
#pragma unroll 8
    for (int i = 0; i < 64; i += 2) {
        a0 = fmaf(xp[i],     w1p[(size_t)i * NH],       a0);
        a1 = fmaf(xp[i + 1], w1p[(size_t)(i + 1) * NH], a1);
    }
    ph[q][j] = a0 + a1;
    __syncthreads();

    if (t < NH) {
        float h = b1[j];
#pragma unroll
        for (int r = 0; r < 8; ++r) h += ph[r][j];
        h = fmaxf(h, 0.0f);
        float v = h * W2[j];
#pragma unroll
        for (int off = 32; off > 0; off >>= 1)
            v += __shfl_down(v, off, 64);
        if ((t & 63) == 0) red[t >> 6] = v;
    }
    __syncthreads();
    if (t == 0) scores[k] = red[0] + red[1] + b2[0];
}

// ---------------- Kernel 2: softmax (in-block) + weighted fuse ----------------
// out[d] = 0.5*global[d] + 0.5*sum_k w[k]*client[k][d], float4-vectorized.
// First PF row-loads are issued into registers BEFORE the softmax so HBM
// latency hides under it; out is stored nontemporally (never re-read).
__global__ void lf_fuse_kernel(const float* __restrict__ client,
                               const float* __restrict__ globalt,
                               const float* __restrict__ scores,
                               float* __restrict__ out,
                               int D4) {
    __shared__ float w[KCLIENTS];
    const int t = threadIdx.x;
    const int d = blockIdx.x * BLOCK + t;
    const bool active = (d < D4);

    const float4* __restrict__ c4 = (const float4*)client;
    const float4* __restrict__ g4 = (const float4*)globalt;
    vfloat4* __restrict__ o4 = (vfloat4*)out;

    // issue first PF row loads (independent of weights)
    float4 pre[PF];
    if (active) {
#pragma unroll
        for (int k = 0; k < PF; ++k)
            pre[k] = c4[(size_t)k * D4 + d];
    }

    // wave 0: softmax over the 64 scores (L2-hot) while loads are in flight
    if (t < KCLIENTS) {
        float s = scores[t];
        float m = s;
#pragma unroll
        for (int off = 32; off > 0; off >>= 1)
            m = fmaxf(m, __shfl_xor(m, off, 64));
        float e = __expf(s - m);
        float sum = e;
#pragma unroll
        for (int off = 32; off > 0; off >>= 1)
            sum += __shfl_xor(sum, off, 64);
        w[t] = e / sum;
    }
    __syncthreads();

    if (active) {
        float4 acc = make_float4(0.f, 0.f, 0.f, 0.f);
#pragma unroll
        for (int k = 0; k < PF; ++k) {
            const float wk = w[k];
            acc.x = fmaf(wk, pre[k].x, acc.x);
            acc.y = fmaf(wk, pre[k].y, acc.y);
            acc.z = fmaf(wk, pre[k].z, acc.z);
            acc.w = fmaf(wk, pre[k].w, acc.w);
        }
#pragma unroll 8
        for (int k = PF; k < KCLIENTS; ++k) {
            const float wk = w[k];
            const float4 c = c4[(size_t)k * D4 + d];
            acc.x = fmaf(wk, c.x, acc.x);
            acc.y = fmaf(wk, c.y, acc.y);
            acc.z = fmaf(wk, c.z, acc.z);
            acc.w = fmaf(wk, c.w, acc.w);
        }
        const float4 g = g4[d];
        vfloat4 r;
        r.x = 0.5f * g.x + 0.5f * acc.x;
        r.y = 0.5f * g.y + 0.5f * acc.y;
        r.z = 0.5f * g.z + 0.5f * acc.z;
        r.w = 0.5f * g.w + 0.5f * acc.w;
        __builtin_nontemporal_store(r, &o4[d]);
    }
}

extern "C" void kernel_launch(void* const* d_in, const int* in_sizes, int n_in,
                              void* d_out, int out_size, void* d_ws, size_t ws_size,
                              hipStream_t stream) {
    const float* client  = (const float*)d_in[0];  // [64, D]
    const float* globalt = (const float*)d_in[1];  // [1, D]
    const float* W1      = (const float*)d_in[2];  // [512, 128]
    const float* b1      = (const float*)d_in[3];  // [128]
    const float* W2      = (const float*)d_in[4];  // [128, 1]
    const float* b2      = (const float*)d_in[5];  // [1]
    float* out = (float*)d_out;                    // [1, D]

    const int D  = in_sizes[0] / KCLIENTS;         // 1,000,000
    const int D4 = D / 4;                          // 250,000

    float* scores = (float*)d_ws;                  // 64 floats

    lf_scores_kernel<<<KCLIENTS, 1024, 0, stream>>>(client, globalt, W1, b1, W2, b2,
                                                    scores, D);

    const int grid = (D4 + BLOCK - 1) / BLOCK;     // 977
    lf_fuse_kernel<<<grid, BLOCK, 0, stream>>>(client, globalt, scores, out, D4);
}